// Round 6
// baseline (329.991 us; speedup 1.0000x reference)
//
#include <hip/hip_runtime.h>

typedef unsigned int uint;
typedef unsigned short ushort_t;
typedef __attribute__((ext_vector_type(8))) short short8;
typedef __attribute__((ext_vector_type(4))) float f32x4;

#define NB 8
#define NC 5
#define NN 512
#define FIN 768
#define NH 4
#define MT 4096   // NB*NN rows, m = b*512+n

__device__ __forceinline__ float b2f(ushort_t u){ uint x = ((uint)u)<<16; return __builtin_bit_cast(float, x); }
__device__ __forceinline__ ushort_t f2b(float f){
  uint u = __builtin_bit_cast(uint, f);
  u += 0x7FFFu + ((u>>16)&1u);
  return (ushort_t)(u>>16);
}
__device__ __forceinline__ ushort_t f2b_fast(float f){
  uint u = __builtin_bit_cast(uint, f);
  return (ushort_t)((u + 0x8000u)>>16);
}

#if __has_builtin(__builtin_amdgcn_cvt_pk_bf16_f32)
typedef __bf16 bf16x2 __attribute__((ext_vector_type(2)));
__device__ __forceinline__ uint pk2(float a, float b){
  return __builtin_bit_cast(uint, __builtin_amdgcn_cvt_pk_bf16_f32(a, b));
}
#else
__device__ __forceinline__ uint pk2(float a, float b){
  return (uint)f2b_fast(a) | ((uint)f2b_fast(b) << 16);
}
#endif

// async global->LDS, 16B/lane; lds base wave-uniform (HW adds lane*16)
#define GLL16(gp, lp) __builtin_amdgcn_global_load_lds( \
    (const __attribute__((address_space(1))) void*)(gp), \
    (__attribute__((address_space(3))) void*)(lp), 16, 0, 0)

// ================ fused prep: conv_h0 | wtrans x3 | adjacency bitpack ================
__global__ __launch_bounds__(256) void prep(const float* __restrict__ x, ushort_t* __restrict__ h0b,
                                            const float* __restrict__ W0, ushort_t* __restrict__ Wt0,
                                            const float* __restrict__ W1, ushort_t* __restrict__ Wt1,
                                            const float* __restrict__ W2, ushort_t* __restrict__ Wt2,
                                            const float* __restrict__ adj, uint* __restrict__ adjB){
  __shared__ float tile[32][33];
  int bid = blockIdx.x, t = threadIdx.x;
  if (bid < 3072){
    int tid = bid*256 + t;                    // over MT*192
    int row = tid/192, q = tid%192;
    int b = row >> 9, n = row & 511;
    float4 v = *(const float4*)(x + ((size_t)(b*NC)*NN + n)*FIN + q*4);
    ushort4 o; o.x = f2b(v.x); o.y = f2b(v.y); o.z = f2b(v.z); o.w = f2b(v.w);
    *(ushort4*)(h0b + (size_t)row*FIN + q*4) = o;
  } else if (bid < 6912){
    const float* W; ushort_t* Wt; int K, N, c, x0, y0;
    if (bid < 4992){ int l = bid-3072; K=768; N=512; W=W0; Wt=Wt0; c=l/384; int r=l%384; x0=r%16; y0=r/16; }
    else if (bid < 6272){ int l = bid-4992; K=512; N=512; W=W1; Wt=Wt1; c=l/256; int r=l%256; x0=r%16; y0=r/16; }
    else { int l = bid-6272; K=512; N=256; W=W2; Wt=Wt2; c=l/128; int r=l%128; x0=r%8; y0=r/8; }
    int n0 = x0*32, k0 = y0*32;
    int tx = t & 31, ty = t >> 5;
    const float* Wp = W + (size_t)c*K*N;
    ushort_t* Wtp = Wt + (size_t)c*K*N;
    #pragma unroll
    for (int r=0;r<4;r++) tile[ty+r*8][tx] = Wp[(size_t)(k0+ty+r*8)*N + n0+tx];
    __syncthreads();
    #pragma unroll
    for (int r=0;r<4;r++) Wtp[(size_t)(n0+ty+r*8)*K + k0+tx] = f2b(tile[tx][ty+r*8]);
  } else {
    int l = bid - 6912;                       // 640: zz*16 + iw
    int iw = l & 15, zz = l >> 4;
    const float* ap = adj + (size_t)zz*NN*NN + (size_t)iw*32*NN;
    uint w0 = 0, w1 = 0;
    #pragma unroll 8
    for (int q=0;q<32;q++){
      if (ap[(size_t)q*NN + t]       > 0.f) w0 |= (1u<<q);
      if (ap[(size_t)q*NN + t + 256] > 0.f) w1 |= (1u<<q);
    }
    adjB[((size_t)zz*16 + iw)*512 + t]       = w0;
    adjB[((size_t)zz*16 + iw)*512 + t + 256] = w1;
  }
}

// ================ MFMA GEMM + fused el/er/exp-table epilogue ================
template<int DH>
__global__ __launch_bounds__(256) void gemm_tn(const ushort_t* __restrict__ A,
                                               const ushort_t* __restrict__ Bt,
                                               ushort_t* __restrict__ Ob,
                                               const float* __restrict__ al, const float* __restrict__ ar,
                                               float* __restrict__ el, float* __restrict__ E1, float* __restrict__ E2,
                                               float* __restrict__ er, float* __restrict__ R1, float* __restrict__ R2,
                                               int K, long a_cs, long b_cs){
  constexpr int DT = NH*DH;
  __shared__ __align__(16) char smem[128*136*2];
  __shared__ float als_s[128], ars_s[128];
  ushort_t* As = (ushort_t*)smem;          // [128 m][32 k]
  ushort_t* Bs = As + 128*32;              // [128 n][32 k]
  ushort_t* St = (ushort_t*)smem;          // epilogue [128 n][136 m]
  int c = blockIdx.z;
  const ushort_t* Ap = A + (size_t)c*a_cs;
  const ushort_t* Bp = Bt + (size_t)c*b_cs;
  int m0 = blockIdx.y*128, n0 = blockIdx.x*128;
  int t = threadIdx.x, lane = t & 63, w = t >> 6;
  int l15 = lane & 15, quad = lane >> 4;
  int wm = (w & 1)*64, wn = (w >> 1)*64;
  if (t < 128){
    als_s[t] = al[(size_t)c*NH*DH + n0 + t];   // (H,D) flattened == local n
    ars_s[t] = ar[(size_t)c*NH*DH + n0 + t];
  }
  f32x4 acc[4][4] = {};
  for (int k0 = 0; k0 < K; k0 += 32){
    __syncthreads();
    {
      int i = t;
      GLL16(Ap + (size_t)(m0 + (i>>2))*K + k0 + (i&3)*8, As + (size_t)(w*64)*8);
      GLL16(Bp + (size_t)(n0 + (i>>2))*K + k0 + (i&3)*8, Bs + (size_t)(w*64)*8);
      i = t + 256;
      GLL16(Ap + (size_t)(m0 + (i>>2))*K + k0 + (i&3)*8, As + (size_t)(w*64 + 256)*8);
      GLL16(Bp + (size_t)(n0 + (i>>2))*K + k0 + (i&3)*8, Bs + (size_t)(w*64 + 256)*8);
    }
    __syncthreads();
    short8 af[4], bfr[4];
    #pragma unroll
    for (int im=0; im<4; im++) af[im] = *(const short8*)(As + (size_t)(wm + im*16 + l15)*32 + quad*8);
    #pragma unroll
    for (int in=0; in<4; in++) bfr[in] = *(const short8*)(Bs + (size_t)(wn + in*16 + l15)*32 + quad*8);
    #pragma unroll
    for (int im=0; im<4; im++)
      #pragma unroll
      for (int in=0; in<4; in++)
        acc[im][in] = __builtin_amdgcn_mfma_f32_16x16x32_bf16(af[im], bfr[in], acc[im][in], 0, 0, 0);
  }
  __syncthreads();
  #pragma unroll
  for (int im=0; im<4; im++)
    #pragma unroll
    for (int in=0; in<4; in++){
      int n = wn + in*16 + l15;
      #pragma unroll
      for (int r=0; r<4; r++){
        int m = wm + im*16 + quad*4 + r;
        St[(size_t)n*136 + m] = f2b(acc[im][in][r]);
      }
    }
  __syncthreads();
  // blocked store
  {
    int n_loc = t >> 1, half = t & 1;
    const ushort_t* srcp = St + (size_t)n_loc*136 + half*64;
    ushort_t* dstc = Ob + (size_t)c*MT*DT;
    #pragma unroll
    for (int q=0;q<8;q++){
      size_t g = (size_t)(m0>>3) + half*8 + q;       // m-cell index (m/8)
      *(short8*)(dstc + (g*DT + n0 + n_loc)*8) = *(const short8*)(srcp + q*8);
    }
  }
  // fused el/er + exp tables
  {
    int m = t >> 1, half = t & 1;
    float sl = 0.f, sr = 0.f;
    const ushort_t* stp = St + (size_t)(half*64)*136 + m;
    #pragma unroll 8
    for (int nn=0; nn<64; nn++){
      float f = b2f(stp[(size_t)nn*136]);
      int n = half*64 + nn;
      sl += f*als_s[n]; sr += f*ars_s[n];
    }
    size_t base = (size_t)c*NH*MT;
    if (DH == 128){
      sl += __shfl_xor(sl, 1); sr += __shfl_xor(sr, 1);
      size_t idx = base + (size_t)(n0>>7)*MT + m0 + m;
      if (half == 0){ el[idx]=sl; E1[idx]=__expf(sl); E2[idx]=__expf(0.2f*sl); }
      else          { er[idx]=sr; R1[idx]=__expf(sr); R2[idx]=__expf(0.2f*sr); }
    } else {
      size_t idx = base + (size_t)((n0>>6)+half)*MT + m0 + m;
      el[idx]=sl; E1[idx]=__expf(sl); E2[idx]=__expf(0.2f*sl);
      er[idx]=sr; R1[idx]=__expf(sr); R2[idx]=__expf(0.2f*sr);
    }
  }
}

// ================ fused attention aggregation (MFMA, j-tile=128) ================
// out[j,d] = (1/max(s_j,1e-9)) * sum_i p[i,j]*feat[i,d] + bias
// p = mask * sel(E1_i,E2_i)*sel(R1_j,R2_j) on sign(el_i+er_j); s_j via ones-MFMA.
// grid: 640 1-D; g = bid%160 (XCD-shared F slice), jt = bid/160 (4 x 128 j).
// Each wave owns 32 j (2 A-frags) -> F-fragment LDS reads serve 2x the j-rows.
template<int DH, int RELU>
__global__ __launch_bounds__(256) void agg(const ushort_t* __restrict__ featB,
                                           const uint* __restrict__ adjB,
                                           const float* __restrict__ el, const float* __restrict__ E1,
                                           const float* __restrict__ E2,
                                           const float* __restrict__ er, const float* __restrict__ R1,
                                           const float* __restrict__ R2,
                                           const float* __restrict__ bias,
                                           ushort_t* __restrict__ outp){
  constexpr int DT = NH*DH;
  constexpr int BN = DH/16;                         // B-frags per step (8 or 4)
  __shared__ __align__(16) ushort_t Fs[2][8*DH*8];  // [buf][isub][d][8i]
  __shared__ float el_s[512], E1_s[512], E2_s[512];
  __shared__ uint Ms[16*128];                       // [iw][jloc]
  int bid = blockIdx.x;
  int g = bid % 160, jt = bid / 160;
  int c = g>>5, b = (g>>2)&7, h = g&3;
  int zz = b*NC + c;
  int j0 = jt*128;
  int t = threadIdx.x, lane = t&63, w = t>>6, l15 = lane&15, quad = lane>>4;
  size_t eb = (size_t)(c*NH + h)*MT + b*NN;
  const ushort_t* fBc = featB + ((size_t)(c*512 + b*64)*DT + h*DH)*8;
  // prologue: per-node tables + mask words into LDS
  el_s[t] = el[eb + t]; el_s[t+256] = el[eb + t+256];
  E1_s[t] = E1[eb + t]; E1_s[t+256] = E1[eb + t+256];
  E2_s[t] = E2[eb + t]; E2_s[t+256] = E2[eb + t+256];
  #pragma unroll
  for (int k=0;k<8;k++){
    int idx = k*256 + t;                            // 2048 = 16 iw x 128 jloc
    Ms[idx] = adjB[((size_t)zz*16 + (idx>>7))*512 + j0 + (idx&127)];
  }
  // per-lane j scalars for the 2 A-frags
  float erv[2], R1v[2], R2v[2];
  #pragma unroll
  for (int im=0; im<2; im++){
    int jme = j0 + w*32 + im*16 + l15;
    erv[im] = er[eb + jme]; R1v[im] = R1[eb + jme]; R2v[im] = R2[eb + jme];
  }
  short8 onesv;
  #pragma unroll
  for (int q=0;q<8;q++) onesv[q] = (short)0x3F80;
  f32x4 acc[2][BN] = {};
  f32x4 accs[2] = {};
  // stage chunk 0
  #pragma unroll
  for (int u=0; u<DH/32; u++){
    int gi = w*(DH/32)+u, isub = gi/(DH/64), part = gi%(DH/64);
    GLL16(fBc + (size_t)isub*DT*8 + part*512 + lane*8, &Fs[0][isub*(DH*8) + part*512]);
  }
  __syncthreads();
  for (int ic = 0; ic < 8; ic++){
    int buf = ic & 1;
    if (ic < 7){
      #pragma unroll
      for (int u=0; u<DH/32; u++){
        int gi = w*(DH/32)+u, isub = gi/(DH/64), part = gi%(DH/64);
        GLL16(fBc + (size_t)((ic+1)*8+isub)*DT*8 + part*512 + lane*8, &Fs[buf^1][isub*(DH*8) + part*512]);
      }
    }
    #pragma unroll
    for (int st=0; st<2; st++){
      int i0c = ic*64 + st*32;
      int iw = i0c >> 5;
      float4 ea  = *(const float4*)&el_s[i0c + quad*8];
      float4 eb4 = *(const float4*)&el_s[i0c + quad*8 + 4];
      float4 x1a = *(const float4*)&E1_s[i0c + quad*8];
      float4 x1b = *(const float4*)&E1_s[i0c + quad*8 + 4];
      float4 x2a = *(const float4*)&E2_s[i0c + quad*8];
      float4 x2b = *(const float4*)&E2_s[i0c + quad*8 + 4];
      float ev[8]  = {ea.x,ea.y,ea.z,ea.w,eb4.x,eb4.y,eb4.z,eb4.w};
      float e1v[8] = {x1a.x,x1a.y,x1a.z,x1a.w,x1b.x,x1b.y,x1b.z,x1b.w};
      float e2v[8] = {x2a.x,x2a.y,x2a.z,x2a.w,x2b.x,x2b.y,x2b.z,x2b.w};
      short8 bfr[BN];
      #pragma unroll
      for (int in=0; in<BN; in++)
        bfr[in] = *(const short8*)&Fs[buf][(st*4+quad)*(DH*8) + (in*16+l15)*8];
      #pragma unroll
      for (int im=0; im<2; im++){
        uint mby = (Ms[iw*128 + w*32 + im*16 + l15] >> (quad*8)) & 0xFFu;
        float pv[8];
        #pragma unroll
        for (int q=0;q<8;q++){
          float s  = ev[q] + erv[im];
          float Ei = (s > 0.f) ? e1v[q] : e2v[q];
          float Rv = (s > 0.f) ? R1v[im] : R2v[im];
          float p  = Ei*Rv;
          pv[q] = ((mby>>q)&1u) ? p : 0.f;
        }
        uint4 pw;
        pw.x = pk2(pv[0], pv[1]); pw.y = pk2(pv[2], pv[3]);
        pw.z = pk2(pv[4], pv[5]); pw.w = pk2(pv[6], pv[7]);
        short8 af = __builtin_bit_cast(short8, pw);
        accs[im] = __builtin_amdgcn_mfma_f32_16x16x32_bf16(af, onesv, accs[im], 0, 0, 0);
        #pragma unroll
        for (int in=0; in<BN; in++)
          acc[im][in] = __builtin_amdgcn_mfma_f32_16x16x32_bf16(af, bfr[in], acc[im][in], 0, 0, 0);
      }
    }
    __syncthreads();
  }
  // epilogue: rows jr = w*32 + im*16 + quad*4+r (C-layout), cols d = in*16+l15
  ushort_t* op = outp + ((size_t)c*MT + b*NN + j0 + w*32)*DT + h*DH;
  float bv[BN];
  #pragma unroll
  for (int in=0; in<BN; in++) bv[in] = bias[(size_t)c*DT + h*DH + in*16 + l15];
  #pragma unroll
  for (int im=0; im<2; im++){
    #pragma unroll
    for (int r=0; r<4; r++){
      int jr = im*16 + quad*4 + r;
      float sinv = 1.f / fmaxf(accs[im][r], 1e-9f);
      #pragma unroll
      for (int in=0; in<BN; in++){
        float o = acc[im][in][r]*sinv + bv[in];
        if (RELU) o = fmaxf(o, 0.f);
        op[(size_t)jr*DT + in*16 + l15] = f2b_fast(o);
      }
    }
  }
}

// ================ head mean ================
__global__ __launch_bounds__(256) void meank(const ushort_t* __restrict__ h2, float* __restrict__ outp){
  int tid = blockIdx.x*256 + threadIdx.x;
  if (tid >= MT*NC*64) return;
  int d = tid & 63; int r = tid >> 6; int c = r % NC; int m = r / NC;
  const ushort_t* p = h2 + ((size_t)c*MT + m)*256 + d;
  float s = 0.25f*(b2f(p[0]) + b2f(p[64]) + b2f(p[128]) + b2f(p[192]));
  outp[(size_t)m*(NC*64) + c*64 + d] = s;
}

extern "C" void kernel_launch(void* const* d_in, const int* in_sizes, int n_in,
                              void* d_out, int out_size, void* d_ws, size_t ws_size,
                              hipStream_t stream){
  const float* x   = (const float*)d_in[0];
  const float* adj = (const float*)d_in[1];
  const float* W0  = (const float*)d_in[2];
  const float* al0 = (const float*)d_in[3];
  const float* ar0 = (const float*)d_in[4];
  const float* b0  = (const float*)d_in[5];
  const float* W1  = (const float*)d_in[6];
  const float* al1 = (const float*)d_in[7];
  const float* ar1 = (const float*)d_in[8];
  const float* b1  = (const float*)d_in[9];
  const float* W2  = (const float*)d_in[10];
  const float* al2 = (const float*)d_in[11];
  const float* ar2 = (const float*)d_in[12];
  const float* b2  = (const float*)d_in[13];

  ushort_t* h0b  = (ushort_t*)d_ws;                 // MT*768
  ushort_t* Wt0  = h0b  + (size_t)MT*FIN;           // 5*512*768
  ushort_t* Wt1  = Wt0  + (size_t)5*512*768;        // 5*512*512
  ushort_t* Wt2  = Wt1  + (size_t)5*512*512;        // 5*256*512
  ushort_t* featB= Wt2  + (size_t)5*256*512;        // 5*MT*512 (blocked [c][m/8][d][8])
  ushort_t* hnat = featB+ (size_t)5*(size_t)MT*512; // 5*MT*512 ([c][m][DT])
  uint*     adjB = (uint*)(hnat + (size_t)5*(size_t)MT*512); // 40*16*512
  float*    elp  = (float*)(adjB + (size_t)40*16*512);       // 6 x NC*NH*MT fp32
  float*    E1p  = elp + (size_t)NC*NH*MT;
  float*    E2p  = E1p + (size_t)NC*NH*MT;
  float*    erp  = E2p + (size_t)NC*NH*MT;
  float*    R1p  = erp + (size_t)NC*NH*MT;
  float*    R2p  = R1p + (size_t)NC*NH*MT;

  prep<<<7552, 256, 0, stream>>>(x, h0b, W0, Wt0, W1, Wt1, W2, Wt2, adj, adjB);

  // layer 0
  gemm_tn<128><<<dim3(4,32,5), 256, 0, stream>>>(h0b, Wt0, featB, al0, ar0,
                                                 elp, E1p, E2p, erp, R1p, R2p,
                                                 768, 0L, (long)512*768);
  agg<128,1><<<640, 256, 0, stream>>>(featB, adjB, elp, E1p, E2p, erp, R1p, R2p, b0, hnat);
  // layer 1
  gemm_tn<128><<<dim3(4,32,5), 256, 0, stream>>>(hnat, Wt1, featB, al1, ar1,
                                                 elp, E1p, E2p, erp, R1p, R2p,
                                                 512, (long)MT*512, (long)512*512);
  agg<128,1><<<640, 256, 0, stream>>>(featB, adjB, elp, E1p, E2p, erp, R1p, R2p, b1, hnat);
  // layer 2 (no relu)
  gemm_tn<64><<<dim3(2,32,5), 256, 0, stream>>>(hnat, Wt2, featB, al2, ar2,
                                                elp, E1p, E2p, erp, R1p, R2p,
                                                512, (long)MT*512, (long)256*512);
  agg<64,0><<<640, 256, 0, stream>>>(featB, adjB, elp, E1p, E2p, erp, R1p, R2p, b2, hnat);

  meank<<<5120, 256, 0, stream>>>(hnat, (float*)d_out);
}

// Round 7
// 300.317 us; speedup vs baseline: 1.0988x; 1.0988x over previous
//
#include <hip/hip_runtime.h>

typedef unsigned int uint;
typedef unsigned short ushort_t;
typedef __attribute__((ext_vector_type(8))) short short8;
typedef __attribute__((ext_vector_type(4))) float f32x4;

#define NB 8
#define NC 5
#define NN 512
#define FIN 768
#define NH 4
#define MT 4096   // NB*NN rows, m = b*512+n

__device__ __forceinline__ float b2f(ushort_t u){ uint x = ((uint)u)<<16; return __builtin_bit_cast(float, x); }
__device__ __forceinline__ ushort_t f2b(float f){
  uint u = __builtin_bit_cast(uint, f);
  u += 0x7FFFu + ((u>>16)&1u);
  return (ushort_t)(u>>16);
}
__device__ __forceinline__ ushort_t f2b_fast(float f){
  uint u = __builtin_bit_cast(uint, f);
  return (ushort_t)((u + 0x8000u)>>16);
}

#if __has_builtin(__builtin_amdgcn_cvt_pk_bf16_f32)
typedef __bf16 bf16x2 __attribute__((ext_vector_type(2)));
__device__ __forceinline__ uint pk2(float a, float b){
  return __builtin_bit_cast(uint, __builtin_amdgcn_cvt_pk_bf16_f32(a, b));
}
#else
__device__ __forceinline__ uint pk2(float a, float b){
  return (uint)f2b_fast(a) | ((uint)f2b_fast(b) << 16);
}
#endif

// async global->LDS, 16B/lane; lds base wave-uniform (HW adds lane*16)
#define GLL16(gp, lp) __builtin_amdgcn_global_load_lds( \
    (const __attribute__((address_space(1))) void*)(gp), \
    (__attribute__((address_space(3))) void*)(lp), 16, 0, 0)

// ================ fused prep: conv_h0 | wtrans x3 | adjacency bitpack ================
__global__ __launch_bounds__(256) void prep(const float* __restrict__ x, ushort_t* __restrict__ h0b,
                                            const float* __restrict__ W0, ushort_t* __restrict__ Wt0,
                                            const float* __restrict__ W1, ushort_t* __restrict__ Wt1,
                                            const float* __restrict__ W2, ushort_t* __restrict__ Wt2,
                                            const float* __restrict__ adj, uint* __restrict__ adjB){
  __shared__ float tile[32][33];
  int bid = blockIdx.x, t = threadIdx.x;
  if (bid < 3072){
    int tid = bid*256 + t;                    // over MT*192
    int row = tid/192, q = tid%192;
    int b = row >> 9, n = row & 511;
    float4 v = *(const float4*)(x + ((size_t)(b*NC)*NN + n)*FIN + q*4);
    ushort4 o; o.x = f2b(v.x); o.y = f2b(v.y); o.z = f2b(v.z); o.w = f2b(v.w);
    *(ushort4*)(h0b + (size_t)row*FIN + q*4) = o;
  } else if (bid < 6912){
    const float* W; ushort_t* Wt; int K, N, c, x0, y0;
    if (bid < 4992){ int l = bid-3072; K=768; N=512; W=W0; Wt=Wt0; c=l/384; int r=l%384; x0=r%16; y0=r/16; }
    else if (bid < 6272){ int l = bid-4992; K=512; N=512; W=W1; Wt=Wt1; c=l/256; int r=l%256; x0=r%16; y0=r/16; }
    else { int l = bid-6272; K=512; N=256; W=W2; Wt=Wt2; c=l/128; int r=l%128; x0=r%8; y0=r/8; }
    int n0 = x0*32, k0 = y0*32;
    int tx = t & 31, ty = t >> 5;
    const float* Wp = W + (size_t)c*K*N;
    ushort_t* Wtp = Wt + (size_t)c*K*N;
    #pragma unroll
    for (int r=0;r<4;r++) tile[ty+r*8][tx] = Wp[(size_t)(k0+ty+r*8)*N + n0+tx];
    __syncthreads();
    #pragma unroll
    for (int r=0;r<4;r++) Wtp[(size_t)(n0+ty+r*8)*K + k0+tx] = f2b(tile[tx][ty+r*8]);
  } else {
    int l = bid - 6912;                       // 640: zz*16 + iw
    int iw = l & 15, zz = l >> 4;
    const float* ap = adj + (size_t)zz*NN*NN + (size_t)iw*32*NN;
    uint w0 = 0, w1 = 0;
    #pragma unroll 8
    for (int q=0;q<32;q++){
      if (ap[(size_t)q*NN + t]       > 0.f) w0 |= (1u<<q);
      if (ap[(size_t)q*NN + t + 256] > 0.f) w1 |= (1u<<q);
    }
    adjB[((size_t)zz*16 + iw)*512 + t]       = w0;
    adjB[((size_t)zz*16 + iw)*512 + t + 256] = w1;
  }
}

// ================ MFMA GEMM + fused el/er/exp-table epilogue ================
template<int DH>
__global__ __launch_bounds__(256) void gemm_tn(const ushort_t* __restrict__ A,
                                               const ushort_t* __restrict__ Bt,
                                               ushort_t* __restrict__ Ob,
                                               const float* __restrict__ al, const float* __restrict__ ar,
                                               float* __restrict__ el, float* __restrict__ E1, float* __restrict__ E2,
                                               float* __restrict__ er, float* __restrict__ R1, float* __restrict__ R2,
                                               int K, long a_cs, long b_cs){
  constexpr int DT = NH*DH;
  __shared__ __align__(16) char smem[128*136*2];
  __shared__ float als_s[128], ars_s[128];
  ushort_t* As = (ushort_t*)smem;          // [128 m][32 k]
  ushort_t* Bs = As + 128*32;              // [128 n][32 k]
  ushort_t* St = (ushort_t*)smem;          // epilogue [128 n][136 m]
  int c = blockIdx.z;
  const ushort_t* Ap = A + (size_t)c*a_cs;
  const ushort_t* Bp = Bt + (size_t)c*b_cs;
  int m0 = blockIdx.y*128, n0 = blockIdx.x*128;
  int t = threadIdx.x, lane = t & 63, w = t >> 6;
  int l15 = lane & 15, quad = lane >> 4;
  int wm = (w & 1)*64, wn = (w >> 1)*64;
  if (t < 128){
    als_s[t] = al[(size_t)c*NH*DH + n0 + t];   // (H,D) flattened == local n
    ars_s[t] = ar[(size_t)c*NH*DH + n0 + t];
  }
  f32x4 acc[4][4] = {};
  for (int k0 = 0; k0 < K; k0 += 32){
    __syncthreads();
    {
      int i = t;
      GLL16(Ap + (size_t)(m0 + (i>>2))*K + k0 + (i&3)*8, As + (size_t)(w*64)*8);
      GLL16(Bp + (size_t)(n0 + (i>>2))*K + k0 + (i&3)*8, Bs + (size_t)(w*64)*8);
      i = t + 256;
      GLL16(Ap + (size_t)(m0 + (i>>2))*K + k0 + (i&3)*8, As + (size_t)(w*64 + 256)*8);
      GLL16(Bp + (size_t)(n0 + (i>>2))*K + k0 + (i&3)*8, Bs + (size_t)(w*64 + 256)*8);
    }
    __syncthreads();
    short8 af[4], bfr[4];
    #pragma unroll
    for (int im=0; im<4; im++) af[im] = *(const short8*)(As + (size_t)(wm + im*16 + l15)*32 + quad*8);
    #pragma unroll
    for (int in=0; in<4; in++) bfr[in] = *(const short8*)(Bs + (size_t)(wn + in*16 + l15)*32 + quad*8);
    #pragma unroll
    for (int im=0; im<4; im++)
      #pragma unroll
      for (int in=0; in<4; in++)
        acc[im][in] = __builtin_amdgcn_mfma_f32_16x16x32_bf16(af[im], bfr[in], acc[im][in], 0, 0, 0);
  }
  __syncthreads();
  #pragma unroll
  for (int im=0; im<4; im++)
    #pragma unroll
    for (int in=0; in<4; in++){
      int n = wn + in*16 + l15;
      #pragma unroll
      for (int r=0; r<4; r++){
        int m = wm + im*16 + quad*4 + r;
        St[(size_t)n*136 + m] = f2b(acc[im][in][r]);
      }
    }
  __syncthreads();
  // blocked store
  {
    int n_loc = t >> 1, half = t & 1;
    const ushort_t* srcp = St + (size_t)n_loc*136 + half*64;
    ushort_t* dstc = Ob + (size_t)c*MT*DT;
    #pragma unroll
    for (int q=0;q<8;q++){
      size_t g = (size_t)(m0>>3) + half*8 + q;       // m-cell index (m/8)
      *(short8*)(dstc + (g*DT + n0 + n_loc)*8) = *(const short8*)(srcp + q*8);
    }
  }
  // fused el/er + exp tables
  {
    int m = t >> 1, half = t & 1;
    float sl = 0.f, sr = 0.f;
    const ushort_t* stp = St + (size_t)(half*64)*136 + m;
    #pragma unroll 8
    for (int nn=0; nn<64; nn++){
      float f = b2f(stp[(size_t)nn*136]);
      int n = half*64 + nn;
      sl += f*als_s[n]; sr += f*ars_s[n];
    }
    size_t base = (size_t)c*NH*MT;
    if (DH == 128){
      sl += __shfl_xor(sl, 1); sr += __shfl_xor(sr, 1);
      size_t idx = base + (size_t)(n0>>7)*MT + m0 + m;
      if (half == 0){ el[idx]=sl; E1[idx]=__expf(sl); E2[idx]=__expf(0.2f*sl); }
      else          { er[idx]=sr; R1[idx]=__expf(sr); R2[idx]=__expf(0.2f*sr); }
    } else {
      size_t idx = base + (size_t)((n0>>6)+half)*MT + m0 + m;
      el[idx]=sl; E1[idx]=__expf(sl); E2[idx]=__expf(0.2f*sl);
      er[idx]=sr; R1[idx]=__expf(sr); R2[idx]=__expf(0.2f*sr);
    }
  }
}

// ================ fused attention aggregation (MFMA, j-tile=64, 32-i dbuf) ================
// out[j,d] = (1/max(s_j,1e-9)) * sum_i p[i,j]*feat[i,d] + bias
// p = mask * sel(E1_i,E2_i)*sel(R1_j,R2_j) on sign(el_i+er_j); s_j via ones-MFMA.
// grid: 1280 1-D, all co-resident at 5 blocks/CU (LDS 26.5KB, VGPR<=102).
// g = bid%160 (XCD-shared F slice), jt = bid/160.
template<int DH, int RELU>
__global__ __launch_bounds__(256,5) void agg(const ushort_t* __restrict__ featB,
                                             const uint* __restrict__ adjB,
                                             const float* __restrict__ el, const float* __restrict__ E1,
                                             const float* __restrict__ E2,
                                             const float* __restrict__ er, const float* __restrict__ R1,
                                             const float* __restrict__ R2,
                                             const float* __restrict__ bias,
                                             ushort_t* __restrict__ outp){
  constexpr int DT = NH*DH;
  constexpr int BN = DH/16;                         // B-frags per step (8 or 4)
  __shared__ __align__(16) ushort_t Fs[2][4*DH*8];  // [buf][isub(4)][d][8i] -- 32 i per buf
  __shared__ float el_s[512], E1_s[512], E2_s[512];
  __shared__ uint Ms[16*64];                        // [iw][jloc]
  int bid = blockIdx.x;
  int g = bid % 160, jt = bid / 160;
  int c = g>>5, b = (g>>2)&7, h = g&3;
  int zz = b*NC + c;
  int j0 = jt*64;
  int t = threadIdx.x, lane = t&63, w = t>>6, l15 = lane&15, quad = lane>>4;
  size_t eb = (size_t)(c*NH + h)*MT + b*NN;
  const ushort_t* fBc = featB + ((size_t)(c*512 + b*64)*DT + h*DH)*8;
  // prologue: per-node tables + mask words into LDS
  el_s[t] = el[eb + t]; el_s[t+256] = el[eb + t+256];
  E1_s[t] = E1[eb + t]; E1_s[t+256] = E1[eb + t+256];
  E2_s[t] = E2[eb + t]; E2_s[t+256] = E2[eb + t+256];
  #pragma unroll
  for (int k=0;k<4;k++){
    int idx = k*256 + t;                            // 1024 = 16 iw x 64 jloc
    Ms[idx] = adjB[((size_t)zz*16 + (idx>>6))*512 + j0 + (idx&63)];
  }
  int jme = j0 + w*16 + l15;                        // this lane's j (A-operand row)
  float erv = er[eb + jme];
  float R1v = R1[eb + jme];
  float R2v = R2[eb + jme];
  short8 onesv;
  #pragma unroll
  for (int q=0;q<8;q++) onesv[q] = (short)0x3F80;
  f32x4 acc[BN] = {};
  f32x4 accs = {0.f,0.f,0.f,0.f};
  // stage chunk 0 (32 i): wave w stages isub w (DH*16 bytes contiguous in global)
  #pragma unroll
  for (int part=0; part<DH/64; part++)
    GLL16(fBc + (size_t)w*DT*8 + part*512 + lane*8, &Fs[0][w*(DH*8) + part*512]);
  __syncthreads();
  for (int ic = 0; ic < 16; ic++){
    int buf = ic & 1;
    if (ic < 15){
      #pragma unroll
      for (int part=0; part<DH/64; part++)
        GLL16(fBc + (size_t)((ic+1)*4+w)*DT*8 + part*512 + lane*8, &Fs[buf^1][w*(DH*8) + part*512]);
    }
    int i0c = ic*32;
    uint mby = (Ms[ic*64 + w*16 + l15] >> (quad*8)) & 0xFFu;
    float4 ea  = *(const float4*)&el_s[i0c + quad*8];
    float4 eb4 = *(const float4*)&el_s[i0c + quad*8 + 4];
    float4 x1a = *(const float4*)&E1_s[i0c + quad*8];
    float4 x1b = *(const float4*)&E1_s[i0c + quad*8 + 4];
    float4 x2a = *(const float4*)&E2_s[i0c + quad*8];
    float4 x2b = *(const float4*)&E2_s[i0c + quad*8 + 4];
    float ev[8]  = {ea.x,ea.y,ea.z,ea.w,eb4.x,eb4.y,eb4.z,eb4.w};
    float e1v[8] = {x1a.x,x1a.y,x1a.z,x1a.w,x1b.x,x1b.y,x1b.z,x1b.w};
    float e2v[8] = {x2a.x,x2a.y,x2a.z,x2a.w,x2b.x,x2b.y,x2b.z,x2b.w};
    float pv[8];
    #pragma unroll
    for (int q=0;q<8;q++){
      float s  = ev[q] + erv;
      float Ei = (s > 0.f) ? e1v[q] : e2v[q];
      float Rv = (s > 0.f) ? R1v : R2v;
      float p  = Ei*Rv;
      pv[q] = ((mby>>q)&1u) ? p : 0.f;
    }
    uint4 pw;
    pw.x = pk2(pv[0], pv[1]); pw.y = pk2(pv[2], pv[3]);
    pw.z = pk2(pv[4], pv[5]); pw.w = pk2(pv[6], pv[7]);
    short8 af = __builtin_bit_cast(short8, pw);
    accs = __builtin_amdgcn_mfma_f32_16x16x32_bf16(af, onesv, accs, 0, 0, 0);
    // B-frags in two groups of BN/2 to cap live VGPRs
    #pragma unroll
    for (int half=0; half<2; half++){
      short8 bfr[BN/2];
      #pragma unroll
      for (int in=0; in<BN/2; in++)
        bfr[in] = *(const short8*)&Fs[buf][quad*(DH*8) + ((half*(BN/2)+in)*16 + l15)*8];
      #pragma unroll
      for (int in=0; in<BN/2; in++)
        acc[half*(BN/2)+in] = __builtin_amdgcn_mfma_f32_16x16x32_bf16(af, bfr[in], acc[half*(BN/2)+in], 0, 0, 0);
    }
    __syncthreads();
  }
  // epilogue: rows jr = quad*4+r (C-layout), cols d = in*16+l15; accs has row sums
  ushort_t* op = outp + ((size_t)c*MT + b*NN + j0 + w*16)*DT + h*DH;
  float bv[BN];
  #pragma unroll
  for (int in=0; in<BN; in++) bv[in] = bias[(size_t)c*DT + h*DH + in*16 + l15];
  #pragma unroll
  for (int r=0; r<4; r++){
    int jr = quad*4 + r;
    float sinv = 1.f / fmaxf(accs[r], 1e-9f);
    #pragma unroll
    for (int in=0; in<BN; in++){
      float o = acc[in][r]*sinv + bv[in];
      if (RELU) o = fmaxf(o, 0.f);
      op[(size_t)jr*DT + in*16 + l15] = f2b_fast(o);
    }
  }
}

// ================ head mean ================
__global__ __launch_bounds__(256) void meank(const ushort_t* __restrict__ h2, float* __restrict__ outp){
  int tid = blockIdx.x*256 + threadIdx.x;
  if (tid >= MT*NC*64) return;
  int d = tid & 63; int r = tid >> 6; int c = r % NC; int m = r / NC;
  const ushort_t* p = h2 + ((size_t)c*MT + m)*256 + d;
  float s = 0.25f*(b2f(p[0]) + b2f(p[64]) + b2f(p[128]) + b2f(p[192]));
  outp[(size_t)m*(NC*64) + c*64 + d] = s;
}

extern "C" void kernel_launch(void* const* d_in, const int* in_sizes, int n_in,
                              void* d_out, int out_size, void* d_ws, size_t ws_size,
                              hipStream_t stream){
  const float* x   = (const float*)d_in[0];
  const float* adj = (const float*)d_in[1];
  const float* W0  = (const float*)d_in[2];
  const float* al0 = (const float*)d_in[3];
  const float* ar0 = (const float*)d_in[4];
  const float* b0  = (const float*)d_in[5];
  const float* W1  = (const float*)d_in[6];
  const float* al1 = (const float*)d_in[7];
  const float* ar1 = (const float*)d_in[8];
  const float* b1  = (const float*)d_in[9];
  const float* W2  = (const float*)d_in[10];
  const float* al2 = (const float*)d_in[11];
  const float* ar2 = (const float*)d_in[12];
  const float* b2  = (const float*)d_in[13];

  ushort_t* h0b  = (ushort_t*)d_ws;                 // MT*768
  ushort_t* Wt0  = h0b  + (size_t)MT*FIN;           // 5*512*768
  ushort_t* Wt1  = Wt0  + (size_t)5*512*768;        // 5*512*512
  ushort_t* Wt2  = Wt1  + (size_t)5*512*512;        // 5*256*512
  ushort_t* featB= Wt2  + (size_t)5*256*512;        // 5*MT*512 (blocked [c][m/8][d][8])
  ushort_t* hnat = featB+ (size_t)5*(size_t)MT*512; // 5*MT*512 ([c][m][DT])
  uint*     adjB = (uint*)(hnat + (size_t)5*(size_t)MT*512); // 40*16*512
  float*    elp  = (float*)(adjB + (size_t)40*16*512);       // 6 x NC*NH*MT fp32
  float*    E1p  = elp + (size_t)NC*NH*MT;
  float*    E2p  = E1p + (size_t)NC*NH*MT;
  float*    erp  = E2p + (size_t)NC*NH*MT;
  float*    R1p  = erp + (size_t)NC*NH*MT;
  float*    R2p  = R1p + (size_t)NC*NH*MT;

  prep<<<7552, 256, 0, stream>>>(x, h0b, W0, Wt0, W1, Wt1, W2, Wt2, adj, adjB);

  // layer 0
  gemm_tn<128><<<dim3(4,32,5), 256, 0, stream>>>(h0b, Wt0, featB, al0, ar0,
                                                 elp, E1p, E2p, erp, R1p, R2p,
                                                 768, 0L, (long)512*768);
  agg<128,1><<<1280, 256, 0, stream>>>(featB, adjB, elp, E1p, E2p, erp, R1p, R2p, b0, hnat);
  // layer 1
  gemm_tn<128><<<dim3(4,32,5), 256, 0, stream>>>(hnat, Wt1, featB, al1, ar1,
                                                 elp, E1p, E2p, erp, R1p, R2p,
                                                 512, (long)MT*512, (long)512*512);
  agg<128,1><<<1280, 256, 0, stream>>>(featB, adjB, elp, E1p, E2p, erp, R1p, R2p, b1, hnat);
  // layer 2 (no relu)
  gemm_tn<64><<<dim3(2,32,5), 256, 0, stream>>>(hnat, Wt2, featB, al2, ar2,
                                                elp, E1p, E2p, erp, R1p, R2p,
                                                512, (long)MT*512, (long)256*512);
  agg<64,0><<<1280, 256, 0, stream>>>(featB, adjB, elp, E1p, E2p, erp, R1p, R2p, b2, hnat);

  meank<<<5120, 256, 0, stream>>>(hnat, (float*)d_out);
}